// Round 7
// baseline (681.866 us; speedup 1.0000x reference)
//
#include <hip/hip_runtime.h>
#include <hip/hip_bf16.h>
#include <hip/hip_fp16.h>

#define TGT 2048
#define BSZ 4
#define EMB 1024
#define NH  16
#define HD  64
#define NTOK (TGT*BSZ)   // 8192
#define BH   (BSZ*NH)    // 64

typedef unsigned short u16;
typedef __attribute__((ext_vector_type(8)))  short        s16x8;
typedef __attribute__((ext_vector_type(8)))  _Float16     f16x8;
typedef __attribute__((ext_vector_type(2)))  _Float16     f16x2;
typedef __attribute__((ext_vector_type(2)))  __fp16       fp16x2;   // cvt_pkrtz return type
typedef __attribute__((ext_vector_type(4)))  float        f32x4;
typedef __attribute__((ext_vector_type(16))) float        f32x16;
typedef __attribute__((ext_vector_type(4)))  unsigned int u32x4;

#define MFMA_BF16(a,b,c)  __builtin_amdgcn_mfma_f32_16x16x32_bf16(a,b,c,0,0,0)
#define MFMA_F16(a,b,c)   __builtin_amdgcn_mfma_f32_16x16x32_f16(a,b,c,0,0,0)
#define MFMA32_F16(a,b,c) __builtin_amdgcn_mfma_f32_32x32x16_f16(a,b,c,0,0,0)

// async global->LDS, 16B per lane; LDS dest = wave-uniform base + lane*16
#define GLOAD_LDS16(gsrc, ldst) \
  __builtin_amdgcn_global_load_lds((const __attribute__((address_space(1))) unsigned int*)(gsrc), \
                                   (__attribute__((address_space(3))) unsigned int*)(ldst), 16, 0, 0)

__device__ __forceinline__ void split_one(float x, u16& h, u16& l) {
  __hip_bfloat16 hb = __float2bfloat16(x);
  float hf = __bfloat162float(hb);
  __hip_bfloat16 lb = __float2bfloat16(x - hf);   // exact remainder, then rounded
  h = *reinterpret_cast<u16*>(&hb);
  l = *reinterpret_cast<u16*>(&lb);
}

// f32 -> (bf16 hi, bf16 lo), vectorized x4
__global__ __launch_bounds__(256) void split_kernel(const float* __restrict__ x,
    u16* __restrict__ hi, u16* __restrict__ lo, int n4) {
  int i = blockIdx.x * 256 + threadIdx.x;
  if (i >= n4) return;
  float4 v = reinterpret_cast<const float4*>(x)[i];
  ushort4 h, l;
  split_one(v.x, h.x, l.x);
  split_one(v.y, h.y, l.y);
  split_one(v.z, h.z, l.z);
  split_one(v.w, h.w, l.w);
  reinterpret_cast<ushort4*>(hi)[i] = h;
  reinterpret_cast<ushort4*>(lo)[i] = l;
}

// Split-bf16 NT GEMM v3: m97 structure + T3/T4 minimum pipeline.
// Double-buffered LDS, prefetch-next issued BEFORE compute, counted vmcnt(8)
// (8 = loads/thread just issued; waits for PREVIOUS stage only), raw s_barrier
// (no implicit drain), lgkmcnt(0)+sched_barrier before the reuse barrier.
// Tile 128x128, BK=32, 4 waves, XOR-swizzled LDS via pre-swizzled source.
template<int EPI>
__global__ __launch_bounds__(256) void gemm_split(
    const u16* __restrict__ Ah, const u16* __restrict__ Al,
    const u16* __restrict__ Bh, const u16* __restrict__ Bl,
    const float* __restrict__ bias, float scale, void* __restrict__ outp, int K)
{
  __shared__ __align__(16) u16 As[2][128*64];   // 2 x 16 KB
  __shared__ __align__(16) u16 Bs[2][128*64];   // 2 x 16 KB
  const int tid  = threadIdx.x;
  const int bm0  = blockIdx.y * 128;
  const int bn0  = blockIdx.x * 128;
  const int wave = tid >> 6, lane = tid & 63, lr = lane & 15, lg = lane >> 4;

  f32x4 zero = {0.f, 0.f, 0.f, 0.f};
  f32x4 acc[2][8];
  #pragma unroll
  for (int i = 0; i < 2; i++)
    #pragma unroll
    for (int j = 0; j < 8; j++) acc[i][j] = zero;

  const u16* srcA[4];
  const u16* srcB[4];
  #pragma unroll
  for (int j = 0; j < 4; j++) {
    int gi  = tid + j*256;
    int row = gi >> 3;
    int lgc = (gi & 7) ^ (row & 7);
    const u16* baA = (lgc < 4) ? Ah : Al;
    const u16* baB = (lgc < 4) ? Bh : Bl;
    srcA[j] = baA + (size_t)(bm0 + row)*K + (lgc & 3)*8;
    srcB[j] = baB + (size_t)(bn0 + row)*K + (lgc & 3)*8;
  }
  const int ldsb = wave*1024;   // wave-uniform chunk base
  const int NT = K >> 5;

  // prologue: stage tile 0 into buf 0
  {
    char* AsB = (char*)As[0];
    char* BsB = (char*)Bs[0];
    #pragma unroll
    for (int j = 0; j < 4; j++) {
      GLOAD_LDS16(srcA[j], AsB + ldsb + j*4096);
      GLOAD_LDS16(srcB[j], BsB + ldsb + j*4096);
    }
  }

  for (int t = 0; t < NT; ++t) {
    const int cur = t & 1;
    if (t + 1 < NT) {
      // issue next-tile loads into the other buffer (its readers finished at
      // the end-of-iteration barrier of t-1), then wait for THIS tile only
      char* AsB = (char*)As[cur ^ 1];
      char* BsB = (char*)Bs[cur ^ 1];
      const int kt = (t + 1) << 5;
      #pragma unroll
      for (int j = 0; j < 4; j++) {
        GLOAD_LDS16(srcA[j] + kt, AsB + ldsb + j*4096);
        GLOAD_LDS16(srcB[j] + kt, BsB + ldsb + j*4096);
      }
      asm volatile("s_waitcnt vmcnt(8)" ::: "memory");
    } else {
      asm volatile("s_waitcnt vmcnt(0)" ::: "memory");
    }
    __builtin_amdgcn_s_barrier();   // buf[cur] staged for ALL waves

    const char* AsB = (const char*)As[cur];
    const char* BsB = (const char*)Bs[cur];
    s16x8 ah[2], al2[2];
    #pragma unroll
    for (int mf = 0; mf < 2; mf++) {
      int row = wave*32 + mf*16 + lr;
      const char* rb = AsB + row*128;
      ah[mf]  = *(const s16x8*)(rb + (((lg    ) ^ (row & 7)) << 4));
      al2[mf] = *(const s16x8*)(rb + (((lg | 4) ^ (row & 7)) << 4));
    }
    #pragma unroll
    for (int nf = 0; nf < 8; nf++) {
      int row = nf*16 + lr;
      const char* rb = BsB + row*128;
      s16x8 bh8 = *(const s16x8*)(rb + (((lg    ) ^ (row & 7)) << 4));
      s16x8 bl8 = *(const s16x8*)(rb + (((lg | 4) ^ (row & 7)) << 4));
      #pragma unroll
      for (int mf = 0; mf < 2; mf++) {
        acc[mf][nf] = MFMA_BF16(al2[mf], bh8, acc[mf][nf]);
        acc[mf][nf] = MFMA_BF16(ah[mf],  bl8, acc[mf][nf]);
        acc[mf][nf] = MFMA_BF16(ah[mf],  bh8, acc[mf][nf]);
      }
    }
    // all my LDS reads complete -> after the barrier, buf[cur^1]'s overwrite
    // in the NEXT iteration cannot race any wave's reads
    asm volatile("s_waitcnt lgkmcnt(0)" ::: "memory");
    __builtin_amdgcn_sched_barrier(0);
    __builtin_amdgcn_s_barrier();
  }

  // Epilogue. D layout (verified m89/m91): col = lane&15, row = (lane>>4)*4 + reg.
  #pragma unroll
  for (int mf = 0; mf < 2; mf++)
    #pragma unroll
    for (int nf = 0; nf < 8; nf++)
      #pragma unroll
      for (int r = 0; r < 4; r++) {
        int m = bm0 + wave*32 + mf*16 + lg*4 + r;
        int n = bn0 + nf*16 + lr;
        float v = (acc[mf][nf][r] + bias[n]) * scale;
        if constexpr (EPI == 0) {        // token m=(t,b), feature n=(h,d) -> (bh,t,d) fp16
          int t = m >> 2, b = m & 3, h = n >> 6, d = n & 63;
          ((_Float16*)outp)[(size_t)((b*NH + h)*TGT + t)*HD + d] = (_Float16)v;
        } else if constexpr (EPI == 1) { // V transposed: (bh,d,s) fp16
          int s = m >> 2, b = m & 3, h = n >> 6, d = n & 63;
          ((_Float16*)outp)[(size_t)((b*NH + h)*HD + d)*TGT + s] = (_Float16)v;
        } else {                         // f32 row-major (final output)
          ((float*)outp)[(size_t)m*EMB + n] = v;
        }
      }
}

// Flash v3 = v2 + T3/T4 minimum pipeline on K/V staging.
// Double-buffered K/V (2 x 16 KB), prefetch-next before compute, counted
// vmcnt(4), raw barriers, lgkmcnt(0) before the reuse barrier.
__global__ __launch_bounds__(256) void flash_kernel(
    const _Float16* __restrict__ Qf, const _Float16* __restrict__ Kf,
    const _Float16* __restrict__ Vt, u16* __restrict__ Oh, u16* __restrict__ Ol,
    float* __restrict__ lse)
{
  __shared__ __align__(16) _Float16 Ks[2][64*64];  // [s][d] 128B rows, swizzled
  __shared__ __align__(16) _Float16 Vs[2][64*64];  // [d][s] 128B rows, swizzled
  const int tid = threadIdx.x, wq = tid >> 6, lane = tid & 63;
  const int lt = lane & 31, hl = lane >> 5;
  const int bh = blockIdx.y, t0 = blockIdx.x * 128;
  const int b = bh >> 4, h = bh & 15;
  const int t = t0 + wq*32 + lt;        // this lane's t-row

  // Q fragments from global (once): qf[kk] holds d = 16kk + 8hl + j, j=0..7
  f16x8 qf[4];
  #pragma unroll
  for (int kk = 0; kk < 4; kk++)
    qf[kk] = *(const f16x8*)&Qf[((size_t)bh*TGT + t)*HD + kk*16 + hl*8];

  float m_run = -1e30f, l_run = 0.f;
  f32x16 accO[2];   // O^T: d = 32df + (r&3)+8*(r>>2)+4hl, col t
  #pragma unroll
  for (int i = 0; i < 16; i++) { accO[0][i] = 0.f; accO[1][i] = 0.f; }

  // per-thread staging sources (advance per tile)
  const int gi0 = tid,       row0 = gi0 >> 3, sg0 = (gi0 & 7) ^ (row0 & 7);
  const int gi1 = tid + 256, row1 = gi1 >> 3, sg1 = (gi1 & 7) ^ (row1 & 7);
  const _Float16* kp0 = Kf + ((size_t)bh*TGT + row0)*HD + sg0*8;
  const _Float16* kp1 = Kf + ((size_t)bh*TGT + row1)*HD + sg1*8;
  const _Float16* vp0 = Vt + ((size_t)bh*HD + row0)*TGT + sg0*8;
  const _Float16* vp1 = Vt + ((size_t)bh*HD + row1)*TGT + sg1*8;

  // prologue: stage tile 0 into buf 0
  {
    char* kb = (char*)Ks[0] + wq*1024;
    char* vb = (char*)Vs[0] + wq*1024;
    GLOAD_LDS16(kp0, kb);
    GLOAD_LDS16(kp1, kb + 4096);
    GLOAD_LDS16(vp0, vb);
    GLOAD_LDS16(vp1, vb + 4096);
  }

  const int NKV = TGT / 64;   // 32
  for (int it = 0; it < NKV; ++it) {
    const int cur = it & 1;
    if (it + 1 < NKV) {
      const size_t ko = (size_t)(it + 1) * 64 * HD;
      const size_t vo = (size_t)(it + 1) * 64;
      char* kb = (char*)Ks[cur ^ 1] + wq*1024;
      char* vb = (char*)Vs[cur ^ 1] + wq*1024;
      GLOAD_LDS16(kp0 + ko, kb);
      GLOAD_LDS16(kp1 + ko, kb + 4096);
      GLOAD_LDS16(vp0 + vo, vb);
      GLOAD_LDS16(vp1 + vo, vb + 4096);
      asm volatile("s_waitcnt vmcnt(4)" ::: "memory");
    } else {
      asm volatile("s_waitcnt vmcnt(0)" ::: "memory");
    }
    __builtin_amdgcn_s_barrier();   // K/V[cur] staged for ALL waves

    const char* KsB = (const char*)Ks[cur];
    const char* VsB = (const char*)Vs[cur];

    // QK^T: sacc[sf] = S[s = 32sf + (r&3)+8(r>>2)+4hl][t]
    f32x16 sacc[2];
    #pragma unroll
    for (int i = 0; i < 16; i++) { sacc[0][i] = 0.f; sacc[1][i] = 0.f; }
    #pragma unroll
    for (int sf = 0; sf < 2; sf++)
      #pragma unroll
      for (int kk = 0; kk < 4; kk++) {
        int row = sf*32 + lt;
        int g = (2*kk + hl) ^ (row & 7);
        f16x8 kfr = *(const f16x8*)(KsB + row*128 + g*16);
        sacc[sf] = MFMA32_F16(kfr, qf[kk], sacc[sf]);
      }

    // online softmax — all per-lane scalars (lane owns one t)
    float pm = -1e30f;
    #pragma unroll
    for (int sf = 0; sf < 2; sf++)
      #pragma unroll
      for (int r = 0; r < 16; r++) pm = fmaxf(pm, sacc[sf][r]);
    pm = fmaxf(pm, __shfl_xor(pm, 32, 64));
    float m_new = fmaxf(m_run, pm);
    float fsc = exp2f(m_run - m_new);
    float psum = 0.f;
    #pragma unroll
    for (int sf = 0; sf < 2; sf++)
      #pragma unroll
      for (int r = 0; r < 16; r++) {
        float p = exp2f(sacc[sf][r] - m_new);
        sacc[sf][r] = p;
        psum += p;
      }
    psum += __shfl_xor(psum, 32, 64);
    l_run = l_run * fsc + psum;
    m_run = m_new;
    accO[0] *= fsc;
    accO[1] *= fsc;

    // P (f32 S-frag) -> fp16 PV A-frags via pack + permlane32_swap; then PV
    #pragma unroll
    for (int sf = 0; sf < 2; sf++) {
      unsigned int P0[4], P1[4];
      #pragma unroll
      for (int q = 0; q < 4; q++) {
        union { fp16x2 h2; unsigned int u; } c0, c1;
        c0.h2 = __builtin_amdgcn_cvt_pkrtz(sacc[sf][4*q],     sacc[sf][4*q + 1]);
        c1.h2 = __builtin_amdgcn_cvt_pkrtz(sacc[sf][4*q + 2], sacc[sf][4*q + 3]);
        P0[q] = c0.u;
        P1[q] = c1.u;
      }
      #pragma unroll
      for (int mp = 0; mp < 2; mp++) {
        unsigned int a0 = P0[2*mp], b0 = P0[2*mp + 1];
        unsigned int a1 = P1[2*mp], b1 = P1[2*mp + 1];
        asm("v_permlane32_swap_b32 %0, %1" : "+v"(a0), "+v"(b0));
        asm("v_permlane32_swap_b32 %0, %1" : "+v"(a1), "+v"(b1));
        union { u32x4 u; f16x8 f; } pw;
        pw.u = (u32x4){a0, a1, b0, b1};   // k = s = 16m + 8hl + j, j=0..7
        const int m = sf*2 + mp;
        #pragma unroll
        for (int df = 0; df < 2; df++) {
          int row = df*32 + lt;
          int g = (2*m + hl) ^ (row & 7);
          f16x8 vfr = *(const f16x8*)(VsB + row*128 + g*16);
          accO[df] = MFMA32_F16(vfr, pw.f, accO[df]);   // O^T[d][t]
        }
      }
    }

    // all my LDS reads complete before the reuse barrier
    asm volatile("s_waitcnt lgkmcnt(0)" ::: "memory");
    __builtin_amdgcn_sched_barrier(0);
    __builtin_amdgcn_s_barrier();
  }

  // epilogue: O row (64 d) per lane, split-bf16, ushort4 stores
  float linv = 1.f / l_run;
  #pragma unroll
  for (int df = 0; df < 2; df++)
    #pragma unroll
    for (int q = 0; q < 4; q++) {
      ushort4 hs, ls;
      float o0 = accO[df][4*q]     * linv;
      float o1 = accO[df][4*q + 1] * linv;
      float o2 = accO[df][4*q + 2] * linv;
      float o3 = accO[df][4*q + 3] * linv;
      split_one(o0, hs.x, ls.x);
      split_one(o1, hs.y, ls.y);
      split_one(o2, hs.z, ls.z);
      split_one(o3, hs.w, ls.w);
      int d0 = 32*df + 8*q + 4*hl;
      size_t idx = ((size_t)t*BSZ + b)*EMB + h*HD + d0;
      *(ushort4*)&Oh[idx] = hs;
      *(ushort4*)&Ol[idx] = ls;
    }
  if (hl == 0)
    lse[(size_t)bh*TGT + t] = m_run + log2f(l_run);
}

// avg_weights: one block per (b, 128t x 128s) tile; loop all 16 heads with
// global_load_lds staging (XOR-swizzled source so ds_read_b128 is conflict-free),
// accumulate p = exp2(S - lse) in registers, single direct global write.
__global__ __launch_bounds__(256) void avg_kernel(
    const _Float16* __restrict__ Qf, const _Float16* __restrict__ Kf,
    const float* __restrict__ lse, float* __restrict__ avgO)
{
  __shared__ __align__(16) _Float16 Qs[128][64];   // 16 KB, 128B rows, XOR-swizzled granules
  __shared__ __align__(16) _Float16 Ks[128][64];   // 16 KB
  __shared__ float lses[NH][128];                  // 8 KB
  const int tid = threadIdx.x, wave = tid >> 6, lane = tid & 63, lr = lane & 15, lg = lane >> 4;

  // XCD-chunked swizzle over 1024 blocks (1024 % 8 == 0 -> bijective)
  int fid = blockIdx.x;
  int nid = (fid & 7) * 128 + (fid >> 3);
  int st = nid & 15, tt = (nid >> 4) & 15, b = nid >> 8;
  int s0 = st * 128, t0 = tt * 128;

  #pragma unroll
  for (int i = 0; i < 8; i++) {
    int idx = tid + i * 256;               // 2048 = 16*128
    int hh = idx >> 7, t = idx & 127;
    lses[hh][t] = lse[(size_t)(b*NH + hh)*TGT + t0 + t];
  }

  f32x4 zero = {0.f, 0.f, 0.f, 0.f};
  f32x4 acc[2][8];
  #pragma unroll
  for (int i = 0; i < 2; i++)
    #pragma unroll
    for (int j = 0; j < 8; j++) acc[i][j] = zero;

  const int rQ = wave * 32;
  const int srcsub = (((lane & 7) ^ (lane >> 3)) << 4) + (lane >> 3) * 128;

  for (int h = 0; h < NH; h++) {
    __syncthreads();
    {
      const char* qb = (const char*)(Qf + ((size_t)(b*NH + h)*TGT + t0) * HD);
      const char* kb = (const char*)(Kf + ((size_t)(b*NH + h)*TGT + s0) * HD);
      const char* gb = (wave < 2) ? qb : kb;
      char* lb = (char*)((wave < 2) ? &Qs[0][0] : &Ks[0][0]);
      const int half = (wave & 1) * 8;
      #pragma unroll
      for (int j = 0; j < 8; j++) {
        int J = half + j;
        GLOAD_LDS16(gb + (size_t)J * 1024 + srcsub, lb + J * 1024);
      }
    }
    __syncthreads();

    float lsr[2][4];
    #pragma unroll
    for (int mf = 0; mf < 2; mf++)
      #pragma unroll
      for (int r = 0; r < 4; r++)
        lsr[mf][r] = lses[h][rQ + mf*16 + lg*4 + r];

    f16x8 aq[2][2];
    #pragma unroll
    for (int mf = 0; mf < 2; mf++)
      #pragma unroll
      for (int kf = 0; kf < 2; kf++) {
        int row = rQ + mf*16 + lr;
        int cb = ((kf*4 + lg) ^ (row & 7)) << 4;
        aq[mf][kf] = *(const f16x8*)((const char*)&Qs[0][0] + row*128 + cb);
      }
    #pragma unroll
    for (int nf = 0; nf < 8; nf++) {
      f32x4 s4[2] = {zero, zero};
      #pragma unroll
      for (int kf = 0; kf < 2; kf++) {
        int row = nf*16 + lr;
        int cb = ((kf*4 + lg) ^ (row & 7)) << 4;
        f16x8 bk = *(const f16x8*)((const char*)&Ks[0][0] + row*128 + cb);
        s4[0] = MFMA_F16(aq[0][kf], bk, s4[0]);
        s4[1] = MFMA_F16(aq[1][kf], bk, s4[1]);
      }
      #pragma unroll
      for (int mf = 0; mf < 2; mf++)
        #pragma unroll
        for (int r = 0; r < 4; r++)
          acc[mf][nf][r] += exp2f(s4[mf][r] - lsr[mf][r]);
    }
  }

  #pragma unroll
  for (int mf = 0; mf < 2; mf++)
    #pragma unroll
    for (int nf = 0; nf < 8; nf++)
      #pragma unroll
      for (int r = 0; r < 4; r++) {
        int ti = t0 + rQ + mf*16 + lg*4 + r;
        int sj = s0 + nf*16 + lr;
        avgO[((size_t)b*TGT + ti)*TGT + sj] = acc[mf][nf][r] * (1.f/16.f);
      }
}

extern "C" void kernel_launch(void* const* d_in, const int* in_sizes, int n_in,
                              void* d_out, int out_size, void* d_ws, size_t ws_size,
                              hipStream_t stream) {
  const float* query = (const float*)d_in[0];
  const float* key_  = (const float*)d_in[1];
  const float* value = (const float*)d_in[2];
  const float* ipw   = (const float*)d_in[3];  // (3072,1024)
  const float* ipb   = (const float*)d_in[4];  // (3072,)
  const float* opw   = (const float*)d_in[5];  // (1024,1024)
  const float* opb   = (const float*)d_in[6];  // (1024,)
  float* out = (float*)d_out;
  float* avg = out + (size_t)TGT*BSZ*EMB;

  char* ws = (char*)d_ws;
  size_t o = 0;
  auto alloc = [&](size_t bytes) { char* p = ws + o; o += bytes; return p; };
  u16* Wh  = (u16*)alloc((size_t)3*EMB*EMB*2);
  u16* Wl  = (u16*)alloc((size_t)3*EMB*EMB*2);
  u16* Woh = (u16*)alloc((size_t)EMB*EMB*2);
  u16* Wol = (u16*)alloc((size_t)EMB*EMB*2);
  u16* Xh  = (u16*)alloc((size_t)NTOK*EMB*2);
  u16* Xl  = (u16*)alloc((size_t)NTOK*EMB*2);
  _Float16* Qf = (_Float16*)alloc((size_t)NTOK*EMB*2);
  _Float16* Kf = (_Float16*)alloc((size_t)NTOK*EMB*2);
  _Float16* Vt = (_Float16*)alloc((size_t)NTOK*EMB*2);
  u16* OhA = (u16*)alloc((size_t)NTOK*EMB*2);
  u16* OlA = (u16*)alloc((size_t)NTOK*EMB*2);
  float* lseA = (float*)alloc((size_t)BH*TGT*4);
  (void)ws_size; (void)in_sizes; (void)n_in; (void)out_size;
  // total ws use: ~128.5 MiB

  const float QSCALE = 0.18033688011112042f;  // log2(e)/8 -> exp2-unit scores

  split_kernel<<<3*EMB*EMB/1024, 256, 0, stream>>>(ipw, Wh, Wl, 3*EMB*EMB/4);
  split_kernel<<<EMB*EMB/1024, 256, 0, stream>>>(opw, Woh, Wol, EMB*EMB/4);

  dim3 ggrid(EMB/128, NTOK/128);
  split_kernel<<<NTOK*EMB/1024, 256, 0, stream>>>(query, Xh, Xl, NTOK*EMB/4);
  gemm_split<0><<<ggrid, 256, 0, stream>>>(Xh, Xl, Wh, Wl, ipb, QSCALE, (void*)Qf, EMB);
  split_kernel<<<NTOK*EMB/1024, 256, 0, stream>>>(key_, Xh, Xl, NTOK*EMB/4);
  gemm_split<0><<<ggrid, 256, 0, stream>>>(Xh, Xl, Wh + (size_t)EMB*EMB, Wl + (size_t)EMB*EMB,
                                           ipb + EMB, 1.0f, (void*)Kf, EMB);
  split_kernel<<<NTOK*EMB/1024, 256, 0, stream>>>(value, Xh, Xl, NTOK*EMB/4);
  gemm_split<1><<<ggrid, 256, 0, stream>>>(Xh, Xl, Wh + (size_t)2*EMB*EMB, Wl + (size_t)2*EMB*EMB,
                                           ipb + 2*EMB, 1.0f, (void*)Vt, EMB);

  flash_kernel<<<dim3(TGT/128, BH), 256, 0, stream>>>(Qf, Kf, Vt, OhA, OlA, lseA);
  avg_kernel<<<1024, 256, 0, stream>>>(Qf, Kf, lseA, avg);
  gemm_split<2><<<ggrid, 256, 0, stream>>>(OhA, OlA, Woh, Wol, opb, 1.0f, (void*)out, EMB);
}